// Round 2
// baseline (16.438 us; speedup 1.0000x reference)
//
#include <hip/hip_runtime.h>

// Problem constants (B, S, I, d) = (8, 32, 64, 256); L = S*I = 2048.
#define NB 8
#define L 2048
#define D 256
#define ROWV (D / 4)   // 64 float4 per row

// Fused stable-compaction scatter. One wave per input row (4 rows/block).
// Each block rebuilds its batch's 2048-bit validity bitmask in LDS (mask is
// L2-resident), then computes each row's destination:
//   valid   l -> rank(l)                      (stable left-pack)
//   invalid l -> total_valid + (l - rank(l))  (stable tail; write zeros)
// The mapping is a bijection on [0, L), so the full output is written every
// call (required: d_out is poisoned once and never restored).
__global__ void __launch_bounds__(256) compact_scatter(
    const float4* __restrict__ in, const int* __restrict__ mask,
    float4* __restrict__ out) {
    __shared__ unsigned long long words[L / 64];  // 32 x u64 = 2048 bits

    const int t = threadIdx.x;
    const int lane = t & 63;
    const int wid = t >> 6;
    const int row0 = blockIdx.x * 4;      // 4 rows per block, same batch (2048 % 4 == 0)
    const int batch = row0 >> 11;         // / L
    const int* m = mask + batch * L;

    // Build bitmask: wave `wid` produces words wid*8 .. wid*8+7 via ballot.
#pragma unroll
    for (int k = 0; k < 8; ++k) {
        const int w = wid * 8 + k;
        const unsigned long long b = __ballot(m[w * 64 + lane] != 0);
        if (lane == 0) words[w] = b;
    }
    __syncthreads();

    const int lb = (row0 & (L - 1)) + wid;  // this wave's row within the batch
    const int wi = lb >> 6;
    const int bi = lb & 63;
    const unsigned long long cur = words[wi];
    const bool valid = (cur >> bi) & 1ull;

    // rank(lb) and total via broadcast LDS reads (wave-uniform addresses).
    int prefix = 0, total = 0;
#pragma unroll
    for (int w = 0; w < L / 64; ++w) {
        const int pc = __popcll(words[w]);
        total += pc;
        if (w < wi) prefix += pc;           // wi is wave-uniform -> scalar branch
    }
    prefix += __popcll(cur & ((1ull << bi) - 1ull));

    const int dest = valid ? prefix : (total + (lb - prefix));

    float4 v = make_float4(0.f, 0.f, 0.f, 0.f);
    if (valid) v = in[(size_t)(batch * L + lb) * ROWV + lane];
    out[(size_t)(batch * L + dest) * ROWV + lane] = v;
}

extern "C" void kernel_launch(void* const* d_in, const int* in_sizes, int n_in,
                              void* d_out, int out_size, void* d_ws, size_t ws_size,
                              hipStream_t stream) {
    const float* ffn_out = (const float*)d_in[0];
    const int* valid_mask = (const int*)d_in[1];  // bool staged as int32 (nonzero = valid)
    float* out = (float*)d_out;

    compact_scatter<<<NB * L / 4, 256, 0, stream>>>(
        (const float4*)ffn_out, valid_mask, (float4*)out);
}

// Round 5
// 12.284 us; speedup vs baseline: 1.3381x; 1.3381x over previous
//
#include <hip/hip_runtime.h>

// Problem constants (B, S, I, d) = (8, 32, 64, 256); L = S*I = 2048.
#define NB 8
#define L 2048
#define D 256
#define ROWV (D / 4)        // 64 float4 per row
#define RPB 16              // rows per block (4 waves x 4 rows)
#define RPW 4               // rows per wave
#define NW (L / 64)         // 32 mask words per batch

// Fused stable-compaction scatter, hardened: exact R2 structure (256 threads,
// per-wave ballot of 8 words, per-wave 32-iter prefix loop) but each wave
// moves 4 consecutive rows (sharing one mask word) instead of 1.
//   valid   l -> rank(l)                      (stable left-pack)
//   invalid l -> total_valid + (l - rank(l))  (stable tail; write zeros)
// Bijection on [0, L) => every output position written each call (d_out is
// poisoned once and never restored).
__global__ void __launch_bounds__(256) compact_scatter(
    const float4* __restrict__ in, const int* __restrict__ mask,
    float4* __restrict__ out) {
    __shared__ unsigned long long words[NW];  // 32 x u64 = 2048 bits

    const int t = threadIdx.x;
    const int lane = t & 63;
    const int wid = t >> 6;                 // 0..3
    const int row0 = blockIdx.x * RPB;      // 16 rows per block, same batch
    const int batch = row0 >> 11;           // / L
    const int* m = mask + batch * L;

    // Ballot phase: wave `wid` produces words wid*8 .. wid*8+7 (as in R2).
#pragma unroll
    for (int k = 0; k < 8; ++k) {
        const int w = wid * 8 + k;
        const unsigned long long b = __ballot(m[w * 64 + lane] != 0);
        if (lane == 0) words[w] = b;
    }
    __syncthreads();

    const int lb0 = (row0 & (L - 1)) + wid * RPW;  // first row of this wave
    const int wi = lb0 >> 6;        // all 4 rows share one mask word (lb0 % 4 == 0)
    const unsigned long long cur = words[wi];

    // Per-wave prefix of valid counts below word wi, plus batch total (as in R2).
    int prefix = 0, total = 0;
#pragma unroll
    for (int w = 0; w < NW; ++w) {
        const int pc = __popcll(words[w]);
        total += pc;
        if (w < wi) prefix += pc;   // wi is wave-uniform -> scalar branch
    }

    const float4 z = make_float4(0.f, 0.f, 0.f, 0.f);
    const size_t base = (size_t)batch * L;

    int dest0, dest1, dest2, dest3;
    float4 v0 = z, v1 = z, v2 = z, v3 = z;
    {
        const int lb = lb0 + 0, bi = lb & 63;
        const bool val = (cur >> bi) & 1ull;
        const int rank = prefix + __popcll(cur & ((1ull << bi) - 1ull));
        dest0 = val ? rank : (total + (lb - rank));
        if (val) v0 = in[(base + lb) * ROWV + lane];
    }
    {
        const int lb = lb0 + 1, bi = lb & 63;
        const bool val = (cur >> bi) & 1ull;
        const int rank = prefix + __popcll(cur & ((1ull << bi) - 1ull));
        dest1 = val ? rank : (total + (lb - rank));
        if (val) v1 = in[(base + lb) * ROWV + lane];
    }
    {
        const int lb = lb0 + 2, bi = lb & 63;
        const bool val = (cur >> bi) & 1ull;
        const int rank = prefix + __popcll(cur & ((1ull << bi) - 1ull));
        dest2 = val ? rank : (total + (lb - rank));
        if (val) v2 = in[(base + lb) * ROWV + lane];
    }
    {
        const int lb = lb0 + 3, bi = lb & 63;
        const bool val = (cur >> bi) & 1ull;
        const int rank = prefix + __popcll(cur & ((1ull << bi) - 1ull));
        dest3 = val ? rank : (total + (lb - rank));
        if (val) v3 = in[(base + lb) * ROWV + lane];
    }

    out[(base + dest0) * ROWV + lane] = v0;
    out[(base + dest1) * ROWV + lane] = v1;
    out[(base + dest2) * ROWV + lane] = v2;
    out[(base + dest3) * ROWV + lane] = v3;
}

extern "C" void kernel_launch(void* const* d_in, const int* in_sizes, int n_in,
                              void* d_out, int out_size, void* d_ws, size_t ws_size,
                              hipStream_t stream) {
    const float* ffn_out = (const float*)d_in[0];
    const int* valid_mask = (const int*)d_in[1];  // bool staged as int32 (nonzero = valid)
    float* out = (float*)d_out;

    compact_scatter<<<NB * L / RPB, 256, 0, stream>>>(
        (const float4*)ffn_out, valid_mask, (float4*)out);
}

// Round 6
// 12.134 us; speedup vs baseline: 1.3546x; 1.0123x over previous
//
#include <hip/hip_runtime.h>

// Problem constants (B, S, I, d) = (8, 32, 64, 256); L = S*I = 2048.
#define NB 8
#define L 2048
#define D 256
#define ROWV (D / 4)        // 64 float4 per row
#define RPB 32              // rows per block (4 waves x 8 rows)
#define RPW 8               // rows per wave
#define NW (L / 64)         // 32 mask words per batch

// Fused stable-compaction scatter. R5 structure (256 threads, per-wave ballot
// of 8 words, per-wave 32-iter prefix loop) with 8 rows per wave. All 8 rows
// of a wave share one 64-bit mask word (lb0 % 8 == 0).
//   valid   l -> rank(l)                      (stable left-pack)
//   invalid l -> total_valid + (l - rank(l))  (stable tail; write zeros)
// Bijection on [0, L) => every output position written each call (d_out is
// poisoned once and never restored).
__global__ void __launch_bounds__(256) compact_scatter(
    const float4* __restrict__ in, const int* __restrict__ mask,
    float4* __restrict__ out) {
    __shared__ unsigned long long words[NW];  // 32 x u64 = 2048 bits

    const int t = threadIdx.x;
    const int lane = t & 63;
    const int wid = t >> 6;                 // 0..3
    const int row0 = blockIdx.x * RPB;      // 32 rows per block, same batch
    const int batch = row0 >> 11;           // / L
    const int* m = mask + batch * L;

    // Ballot phase: wave `wid` produces words wid*8 .. wid*8+7 (as in R5).
#pragma unroll
    for (int k = 0; k < 8; ++k) {
        const int w = wid * 8 + k;
        const unsigned long long b = __ballot(m[w * 64 + lane] != 0);
        if (lane == 0) words[w] = b;
    }
    __syncthreads();

    const int lb0 = (row0 & (L - 1)) + wid * RPW;  // first row of this wave
    const int wi = lb0 >> 6;        // all 8 rows share one mask word (lb0 % 8 == 0)
    const unsigned long long cur = words[wi];

    // Per-wave prefix of valid counts below word wi, plus batch total.
    int prefix = 0, total = 0;
#pragma unroll
    for (int w = 0; w < NW; ++w) {
        const int pc = __popcll(words[w]);
        total += pc;
        if (w < wi) prefix += pc;   // wi is wave-uniform -> scalar branch
    }

    const float4 z = make_float4(0.f, 0.f, 0.f, 0.f);
    const size_t base = (size_t)batch * L;

    // Named scalars only (register arrays crashed in R3/R4).
    int dest0, dest1, dest2, dest3, dest4, dest5, dest6, dest7;
    float4 v0 = z, v1 = z, v2 = z, v3 = z, v4 = z, v5 = z, v6 = z, v7 = z;

#define ROW_BODY(r)                                                        \
    {                                                                      \
        const int lb = lb0 + r, bi = lb & 63;                              \
        const bool val = (cur >> bi) & 1ull;                               \
        const int rank = prefix + __popcll(cur & ((1ull << bi) - 1ull));   \
        dest##r = val ? rank : (total + (lb - rank));                      \
        if (val) v##r = in[(base + lb) * ROWV + lane];                     \
    }

    ROW_BODY(0) ROW_BODY(1) ROW_BODY(2) ROW_BODY(3)
    ROW_BODY(4) ROW_BODY(5) ROW_BODY(6) ROW_BODY(7)
#undef ROW_BODY

    out[(base + dest0) * ROWV + lane] = v0;
    out[(base + dest1) * ROWV + lane] = v1;
    out[(base + dest2) * ROWV + lane] = v2;
    out[(base + dest3) * ROWV + lane] = v3;
    out[(base + dest4) * ROWV + lane] = v4;
    out[(base + dest5) * ROWV + lane] = v5;
    out[(base + dest6) * ROWV + lane] = v6;
    out[(base + dest7) * ROWV + lane] = v7;
}

extern "C" void kernel_launch(void* const* d_in, const int* in_sizes, int n_in,
                              void* d_out, int out_size, void* d_ws, size_t ws_size,
                              hipStream_t stream) {
    const float* ffn_out = (const float*)d_in[0];
    const int* valid_mask = (const int*)d_in[1];  // bool staged as int32 (nonzero = valid)
    float* out = (float*)d_out;

    compact_scatter<<<NB * L / RPB, 256, 0, stream>>>(
        (const float4*)ffn_out, valid_mask, (float4*)out);
}

// Round 7
// 11.266 us; speedup vs baseline: 1.4591x; 1.0771x over previous
//
#include <hip/hip_runtime.h>

// Problem constants (B, S, I, d) = (8, 32, 64, 256); L = S*I = 2048.
#define NB 8
#define L 2048
#define D 256
#define ROWV (D / 4)        // 64 float4 per row
#define RPB 32              // rows per block (4 waves x 8 rows)
#define RPW 8               // rows per wave
#define NW (L / 64)         // 32 mask words per batch

// Fused stable-compaction scatter, barrier-free. Each wave:
//  1. ballots its OWN mask word (the 8 rows it moves share one 64-bit word),
//  2. immediately issues its 8 conditional payload loads (overlap!),
//  3. re-ballots all 32 words of the batch (L1/L2-resident mask) to get
//     prefix (valid count below its word) and total (batch valid count),
//  4. computes destinations and stores.
//   valid   l -> rank(l)                      (stable left-pack)
//   invalid l -> total_valid + (l - rank(l))  (stable tail; write zeros)
// Bijection on [0, L) => every output position written each call (d_out is
// poisoned once and never restored). No LDS, no __syncthreads => no
// vmcnt(0) barrier drain; rank math hides under payload-load latency.
__global__ void __launch_bounds__(256) compact_scatter(
    const float4* __restrict__ in, const int* __restrict__ mask,
    float4* __restrict__ out) {
    const int t = threadIdx.x;
    const int lane = t & 63;
    const int wid = t >> 6;                 // 0..3
    const int row0 = blockIdx.x * RPB;      // 32 rows per block, same batch
    const int batch = row0 >> 11;           // / L
    const int* m = mask + batch * L;

    const int lb0 = (row0 & (L - 1)) + wid * RPW;  // first row of this wave
    const int wi = lb0 >> 6;        // all 8 rows share one mask word (lb0 % 8 == 0)

    // Step 1: own-word ballot (no LDS, no sync needed).
    const unsigned long long cur = __ballot(m[wi * 64 + lane] != 0);

    const float4 z = make_float4(0.f, 0.f, 0.f, 0.f);
    const size_t base = (size_t)batch * L;

    // Step 2: issue payload loads NOW (val/lrank depend only on cur).
    // Named scalars only (register arrays crashed in R3/R4).
#define ROW_PRE(r)                                                          \
    const int bi##r = (lb0 + r) & 63;                                       \
    const bool val##r = (cur >> bi##r) & 1ull;                              \
    const int lrank##r = __popcll(cur & ((1ull << bi##r) - 1ull));          \
    float4 v##r = z;                                                        \
    if (val##r) v##r = in[(base + lb0 + r) * ROWV + lane];

    ROW_PRE(0) ROW_PRE(1) ROW_PRE(2) ROW_PRE(3)
    ROW_PRE(4) ROW_PRE(5) ROW_PRE(6) ROW_PRE(7)
#undef ROW_PRE

    // Step 3: full-batch scan via ballots (mask is L1/L2-resident; this
    // VALU/L2 work overlaps the in-flight payload loads above).
    int prefix = 0, total = 0;
#pragma unroll
    for (int w = 0; w < NW; ++w) {
        const unsigned long long bw = __ballot(m[w * 64 + lane] != 0);
        const int pc = __popcll(bw);
        total += pc;
        if (w < wi) prefix += pc;   // wi is wave-uniform -> scalar branch
    }

    // Step 4: destinations + stores.
#define ROW_POST(r)                                                         \
    {                                                                       \
        const int rank = prefix + lrank##r;                                 \
        const int dest = val##r ? rank : (total + (lb0 + r - rank));        \
        out[(base + dest) * ROWV + lane] = v##r;                            \
    }

    ROW_POST(0) ROW_POST(1) ROW_POST(2) ROW_POST(3)
    ROW_POST(4) ROW_POST(5) ROW_POST(6) ROW_POST(7)
#undef ROW_POST
}

extern "C" void kernel_launch(void* const* d_in, const int* in_sizes, int n_in,
                              void* d_out, int out_size, void* d_ws, size_t ws_size,
                              hipStream_t stream) {
    const float* ffn_out = (const float*)d_in[0];
    const int* valid_mask = (const int*)d_in[1];  // bool staged as int32 (nonzero = valid)
    float* out = (float*)d_out;

    compact_scatter<<<NB * L / RPB, 256, 0, stream>>>(
        (const float4*)ffn_out, valid_mask, (float4*)out);
}

// Round 9
// 10.724 us; speedup vs baseline: 1.5328x; 1.0506x over previous
//
#include <hip/hip_runtime.h>

// Problem constants (B, S, I, d) = (8, 32, 64, 256); L = S*I = 2048.
#define NB 8
#define L 2048
#define D 256
#define ROWV (D / 4)        // 64 float4-sized chunks per row
#define RPB 32              // rows per block (4 waves x 8 rows)
#define RPW 8               // rows per wave
#define NW (L / 64)         // 32 mask words per batch

// Native vector type: __builtin_nontemporal_* rejects HIP_vector_type
// (struct), but accepts clang ext_vector_type.
typedef float f4 __attribute__((ext_vector_type(4)));

// Payload is stream-once (no reuse): nontemporal loads/stores keep the 32 MB
// stream from evicting the (reused) mask out of L2. Mask loads stay cacheable.
static __device__ __forceinline__ f4 nt_load(const f4* p) {
    return __builtin_nontemporal_load(p);
}
static __device__ __forceinline__ void nt_store(f4* p, f4 v) {
    __builtin_nontemporal_store(v, p);
}

// Fused stable-compaction scatter, barrier-free (R7 structure). Each wave:
//  1. ballots its OWN mask word (its 8 rows share one 64-bit word),
//  2. immediately issues its 8 conditional payload loads (overlap),
//  3. re-ballots all 32 words of the batch (L1/L2-resident mask) to get
//     prefix (valid count below its word) and total (batch valid count),
//  4. computes destinations and stores.
//   valid   l -> rank(l)                      (stable left-pack)
//   invalid l -> total_valid + (l - rank(l))  (stable tail; write zeros)
// Bijection on [0, L) => every output position written each call (d_out is
// poisoned once and never restored).
__global__ void __launch_bounds__(256) compact_scatter(
    const f4* __restrict__ in, const int* __restrict__ mask,
    f4* __restrict__ out) {
    const int t = threadIdx.x;
    const int lane = t & 63;
    const int wid = t >> 6;                 // 0..3
    const int row0 = blockIdx.x * RPB;      // 32 rows per block, same batch
    const int batch = row0 >> 11;           // / L
    const int* m = mask + batch * L;

    const int lb0 = (row0 & (L - 1)) + wid * RPW;  // first row of this wave
    const int wi = lb0 >> 6;        // all 8 rows share one mask word (lb0 % 8 == 0)

    // Step 1: own-word ballot (no LDS, no sync needed).
    const unsigned long long cur = __ballot(m[wi * 64 + lane] != 0);

    const f4 z = (f4){0.f, 0.f, 0.f, 0.f};
    const size_t base = (size_t)batch * L;

    // Step 2: issue payload loads NOW (val/lrank depend only on cur).
    // Named scalars only (register arrays crashed in R3/R4).
#define ROW_PRE(r)                                                          \
    const int bi##r = (lb0 + r) & 63;                                       \
    const bool val##r = (cur >> bi##r) & 1ull;                              \
    const int lrank##r = __popcll(cur & ((1ull << bi##r) - 1ull));          \
    f4 v##r = z;                                                            \
    if (val##r) v##r = nt_load(&in[(base + lb0 + r) * ROWV + lane]);

    ROW_PRE(0) ROW_PRE(1) ROW_PRE(2) ROW_PRE(3)
    ROW_PRE(4) ROW_PRE(5) ROW_PRE(6) ROW_PRE(7)
#undef ROW_PRE

    // Step 3: full-batch scan via ballots (mask is L1/L2-resident; this
    // VALU/L2 work overlaps the in-flight payload loads above).
    int prefix = 0, total = 0;
#pragma unroll
    for (int w = 0; w < NW; ++w) {
        const unsigned long long bw = __ballot(m[w * 64 + lane] != 0);
        const int pc = __popcll(bw);
        total += pc;
        if (w < wi) prefix += pc;   // wi is wave-uniform -> scalar branch
    }

    // Step 4: destinations + stores.
#define ROW_POST(r)                                                         \
    {                                                                       \
        const int rank = prefix + lrank##r;                                 \
        const int dest = val##r ? rank : (total + (lb0 + r - rank));        \
        nt_store(&out[(base + dest) * ROWV + lane], v##r);                  \
    }

    ROW_POST(0) ROW_POST(1) ROW_POST(2) ROW_POST(3)
    ROW_POST(4) ROW_POST(5) ROW_POST(6) ROW_POST(7)
#undef ROW_POST
}

extern "C" void kernel_launch(void* const* d_in, const int* in_sizes, int n_in,
                              void* d_out, int out_size, void* d_ws, size_t ws_size,
                              hipStream_t stream) {
    const float* ffn_out = (const float*)d_in[0];
    const int* valid_mask = (const int*)d_in[1];  // bool staged as int32 (nonzero = valid)
    float* out = (float*)d_out;

    compact_scatter<<<NB * L / RPB, 256, 0, stream>>>(
        (const f4*)ffn_out, valid_mask, (f4*)out);
}